// Round 4
// baseline (82.508 us; speedup 1.0000x reference)
//
#include <hip/hip_runtime.h>

#define BB 32
#define SS 2048
#define HH 768
#define LL 9
#define NROWS (BB * SS)  // 65536
#define NCHUNK 64
#define TCHUNK 32        // SS / NCHUNK
#define RPB 8            // rows per block (gemm)
#define PASSES 4         // RPB / 2 row-streams
#define GEMM_BLOCKS (NROWS / RPB)  // 8192

// ---------------------------------------------------------------------------
// stable logsumexp over 9 values
__device__ __forceinline__ float lse9(const float* v) {
  float m = fmaxf(fmaxf(fmaxf(fmaxf(v[0], v[1]), fmaxf(v[2], v[3])),
                        fmaxf(fmaxf(v[4], v[5]), fmaxf(v[6], v[7]))),
                  v[8]);
  float s = 0.f;
#pragma unroll
  for (int k = 0; k < 9; ++k) s += __expf(v[k] - m);
  return m + __logf(s);
}

// ---------------------------------------------------------------------------
// Kernel 1: emissions = hs @ W^T + b.
// 2 row-streams x 2 k-halves per 256-thread block. NO cross-lane reduction:
// each lane writes 9 partials to LDS (bank-free: 9*lane mod 32 coprime);
// a 72-thread tail does the 128-way combine. In-place 2-buffer prefetch
// (depth 2), __launch_bounds__(256,4) pins 4 waves/SIMD (~110 VGPR demand).
__global__ __launch_bounds__(256, 4)
void emis_gemm(const float* __restrict__ hs, const float* __restrict__ W,
               const float* __restrict__ bias, float* __restrict__ em,
               int* __restrict__ gcnt) {
  const int tid = threadIdx.x;
  const int lane = tid & 63;
  const int w = tid >> 6;   // wave 0..3
  const int pair = w >> 1;  // row stream
  const int half = w & 1;   // k half
  const int rowbase = blockIdx.x * RPB;
  const int kb = half * 384;
  if (blockIdx.x == 0 && tid == 0) *gcnt = 0;  // re-arm fold's finalize counter

  __shared__ float part[RPB][129][9];  // 37.1 KB; 129 pads combine-phase banks

  // per-lane W slice: 9 labels x 6 k-values = 54 VGPRs (L1/L2-served)
  float wr[LL][6];
#pragma unroll
  for (int l = 0; l < LL; ++l) {
    float4 t4 = *reinterpret_cast<const float4*>(W + l * HH + kb + lane * 4);
    float2 t2 = *reinterpret_cast<const float2*>(W + l * HH + kb + 256 + lane * 2);
    wr[l][0] = t4.x; wr[l][1] = t4.y; wr[l][2] = t4.z; wr[l][3] = t4.w;
    wr[l][4] = t2.x; wr[l][5] = t2.y;
  }

  const int Lp = half * 64 + lane;  // partial slot 0..127
  // prime passes 0 and 1
  const float* rA = hs + (size_t)(rowbase + 0 + pair) * HH + kb;
  float4 A4 = *reinterpret_cast<const float4*>(rA + lane * 4);
  float2 A2 = *reinterpret_cast<const float2*>(rA + 256 + lane * 2);
  const float* rB = hs + (size_t)(rowbase + 2 + pair) * HH + kb;
  float4 B4 = *reinterpret_cast<const float4*>(rB + lane * 4);
  float2 B2 = *reinterpret_cast<const float2*>(rB + 256 + lane * 2);

#pragma unroll
  for (int p = 0; p < PASSES; ++p) {
    float4 cur4 = (p & 1) ? B4 : A4;
    float2 cur2 = (p & 1) ? B2 : A2;
    if (p + 2 < PASSES) {  // refill the consumed buffer for pass p+2 (static)
      const float* rn = hs + (size_t)(rowbase + (p + 2) * 2 + pair) * HH + kb;
      if (p & 1) {
        B4 = *reinterpret_cast<const float4*>(rn + lane * 4);
        B2 = *reinterpret_cast<const float2*>(rn + 256 + lane * 2);
      } else {
        A4 = *reinterpret_cast<const float4*>(rn + lane * 4);
        A2 = *reinterpret_cast<const float2*>(rn + 256 + lane * 2);
      }
    }
    const float h[6] = {cur4.x, cur4.y, cur4.z, cur4.w, cur2.x, cur2.y};
    const int o = p * 2 + pair;
#pragma unroll
    for (int l = 0; l < LL; ++l) {
      float s = h[0] * wr[l][0];
#pragma unroll
      for (int q = 1; q < 6; ++q) s = fmaf(h[q], wr[l][q], s);
      part[o][Lp][l] = s;
    }
  }
  __syncthreads();

  // combine 128 partials per (row,label); 72 active threads
  if (tid < RPB * LL) {
    const int o = tid / LL, l = tid - o * LL;
    float s = bias[l];
#pragma unroll 8
    for (int q = 0; q < 128; ++q) s += part[o][q][l];
    em[(size_t)(rowbase + o) * LL + l] = s;
  }
}

// ---------------------------------------------------------------------------
// Kernel 2: per-chunk transfer matrix + numerator partial (fused).
__global__ __launch_bounds__(128)
void crf_chunk(const float* __restrict__ em, const int* __restrict__ lab,
               const float* __restrict__ trans, const float* __restrict__ startT,
               float* __restrict__ Pout, float* __restrict__ numpart,
               int* __restrict__ cntpart) {
  const int blk = blockIdx.x;
  const int b = blk >> 6, c = blk & 63;
  const int tid = threadIdx.x;
  const int lane = tid & 63;
  const int wv = tid >> 6;
  __shared__ float em_s[TCHUNK * LL];
  __shared__ int lab_s[TCHUNK + 1];
  __shared__ float Pbuf[2][81];

  const int t0 = c * TCHUNK;
  const size_t ebase = (size_t)(b * SS + t0) * LL;
  for (int i = tid; i < TCHUNK * LL; i += 128) em_s[i] = em[ebase + i];
  if (tid <= TCHUNK) {
    int g = t0 - 1 + tid;
    lab_s[tid] = (g >= 0) ? lab[b * SS + g] : 0;
  }
  const int i9 = tid / 9, j9 = tid % 9;
  float tc[9];
  if (tid < 81) {
#pragma unroll
    for (int k = 0; k < 9; ++k) tc[k] = trans[k * 9 + j9];
  }
  __syncthreads();

  unsigned long long mb =
      __ballot((lane < 32) ? (lab_s[1 + lane] != -100) : false);
  unsigned mask32 = (unsigned)mb;

  if (wv == 1) {
    float sc = 0.f;
    if (lane < 32) {
      int lv = lab_s[1 + lane];
      int tg = (lv != -100) ? lv : 0;
      if (t0 + lane == 0) {
        sc = startT[tg] + em_s[tg];
      } else if (lv != -100) {
        int pv = lab_s[lane];
        int tp = (pv != -100) ? pv : 0;
        sc = trans[tp * LL + tg] + em_s[lane * LL + tg];
      }
    }
#pragma unroll
    for (int off = 32; off; off >>= 1) sc += __shfl_xor(sc, off, 64);
    if (lane == 0) {
      numpart[blk] = sc;
      cntpart[blk] = __popc(mask32);
    }
  }

  if (tid < 81) Pbuf[0][tid] = (i9 == j9) ? 0.f : -1e30f;
  __syncthreads();
  int cur = 0;
  const int ltstart = (c == 0) ? 1 : 0;  // t=0 is alpha0, not a matrix
  for (int lt = ltstart; lt < TCHUNK; ++lt) {
    if ((mask32 >> lt) & 1u) {
      if (tid < 81) {
        float v[9];
#pragma unroll
        for (int k = 0; k < 9; ++k) v[k] = Pbuf[cur][i9 * 9 + k] + tc[k];
        Pbuf[cur ^ 1][tid] = lse9(v) + em_s[lt * LL + j9];
      }
      __syncthreads();
      cur ^= 1;
    }
  }
  if (tid < 81) Pout[(size_t)blk * 81 + tid] = Pbuf[cur][tid];
}

// ---------------------------------------------------------------------------
// Kernel 3: per-batch tree fold (depth 6) + llh + fused finalize.
// Last block (device-scope counter) sums llh in fixed order -> out[0].
__global__ __launch_bounds__(128)
void crf_fold(const float* __restrict__ Pm, const float* __restrict__ em,
              const float* __restrict__ startT, const float* __restrict__ endT,
              const float* __restrict__ numpart, const int* __restrict__ cntpart,
              const int* __restrict__ lab, float* __restrict__ llh,
              int* __restrict__ gcnt, float* __restrict__ out) {
  const int b = blockIdx.x, tid = threadIdx.x;
  __shared__ __align__(16) float Abuf[64 * 81];
  __shared__ __align__(16) float Bbuf[32 * 81];

  const float* src = Pm + (size_t)b * NCHUNK * 81;  // 16B-aligned slab
  for (int i = tid; i < 64 * 81 / 4; i += 128)
    reinterpret_cast<float4*>(Abuf)[i] = reinterpret_cast<const float4*>(src)[i];
  __syncthreads();

  float* pin = Abuf;
  float* pout = Bbuf;
  for (int n = 32;; n >>= 1) {
    for (int o = tid; o < n * 81; o += 128) {
      int m = o / 81, e = o % 81;
      int i = e / 9, j = e % 9;
      const float* M1 = pin + (2 * m) * 81;
      const float* M2 = pin + (2 * m + 1) * 81;
      float v[9];
#pragma unroll
      for (int k = 0; k < 9; ++k) v[k] = M1[i * 9 + k] + M2[k * 9 + j];
      pout[o] = lse9(v);
    }
    __syncthreads();
    if (n == 1) break;
    float* t = pin; pin = pout;
    pout = (pout == Bbuf) ? Abuf : t;
  }
  const float* fin = pout;

  float ns = 0.f;
  int cn = 0;
  if (tid < 64) {
    ns = numpart[b * 64 + tid];
    cn = cntpart[b * 64 + tid];
#pragma unroll
    for (int off = 32; off; off >>= 1) {
      ns += __shfl_xor(ns, off, 64);
      cn += __shfl_xor(cn, off, 64);
    }
  }
  if (tid == 0) {
    float a0[9], af[9], v[9];
#pragma unroll
    for (int j = 0; j < 9; ++j) a0[j] = startT[j] + em[(size_t)b * SS * LL + j];
#pragma unroll
    for (int j = 0; j < 9; ++j) {
#pragma unroll
      for (int k = 0; k < 9; ++k) v[k] = a0[k] + fin[k * 9 + j];
      af[j] = lse9(v);
    }
#pragma unroll
    for (int j = 0; j < 9; ++j) v[j] = af[j] + endT[j];
    float den = lse9(v);
    int se = cn - 1;
    int lt = lab[b * SS + se];
    if (lt == -100) lt = 0;
    llh[b] = (ns + endT[lt]) - den;

    __threadfence();                   // publish llh[b] (device scope)
    int old = atomicAdd(gcnt, 1);
    if (old == BB - 1) {               // last block finalizes, fixed order
      __threadfence();
      float s = 0.f;
      for (int i = 0; i < BB; ++i)
        s += __hip_atomic_load(&llh[i], __ATOMIC_RELAXED,
                               __HIP_MEMORY_SCOPE_AGENT);
      out[0] = -s / (float)BB;
    }
  }
}

// ---------------------------------------------------------------------------
extern "C" void kernel_launch(void* const* d_in, const int* in_sizes, int n_in,
                              void* d_out, int out_size, void* d_ws, size_t ws_size,
                              hipStream_t stream) {
  const float* hs = (const float*)d_in[0];
  const float* W = (const float*)d_in[1];
  const float* bias = (const float*)d_in[2];
  const float* startT = (const float*)d_in[3];
  const float* endT = (const float*)d_in[4];
  const float* trans = (const float*)d_in[5];
  const int* labels = (const int*)d_in[6];

  float* out = (float*)d_out;  // out[0] = loss, out[1..] = emissions [B,S,L]
  float* em = out + 1;

  float* wsf = (float*)d_ws;
  float* llh = wsf;                       // [32]
  int* gcnt = (int*)(wsf + 32);           // [1]
  float* numpart = wsf + 64;              // [B*NCHUNK]
  int* cntpart = (int*)(wsf + 64 + 2048); // [B*NCHUNK]
  float* Pm = wsf + 64 + 4096;            // [B*NCHUNK*81], 16B-aligned

  emis_gemm<<<GEMM_BLOCKS, 256, 0, stream>>>(hs, W, bias, em, gcnt);
  crf_chunk<<<BB * NCHUNK, 128, 0, stream>>>(em, labels, trans, startT,
                                             Pm, numpart, cntpart);
  crf_fold<<<BB, 128, 0, stream>>>(Pm, em, startT, endT, numpart, cntpart,
                                   labels, llh, gcnt, out);
}

// Round 5
// 79.912 us; speedup vs baseline: 1.0325x; 1.0325x over previous
//
#include <hip/hip_runtime.h>

#define BB 32
#define SS 2048
#define HH 768
#define LL 9
#define NROWS (BB * SS)  // 65536
#define NCHUNK 64
#define TCHUNK 32        // rows per chunk block

// ---------------------------------------------------------------------------
// stable logsumexp over 9 values
__device__ __forceinline__ float lse9(const float* v) {
  float m = fmaxf(fmaxf(fmaxf(fmaxf(v[0], v[1]), fmaxf(v[2], v[3])),
                        fmaxf(fmaxf(v[4], v[5]), fmaxf(v[6], v[7]))),
                  v[8]);
  float s = 0.f;
#pragma unroll
  for (int k = 0; k < 9; ++k) s += __expf(v[k] - m);
  return m + __logf(s);
}

// ---------------------------------------------------------------------------
// DPP add on the VALU pipe (no DS ops). CTRL is an ICE via template.
template <int CTRL>
__device__ __forceinline__ float dpp_add(float x) {
  int t = __builtin_amdgcn_update_dpp(0, __float_as_int(x), CTRL, 0xf, 0xf, true);
  return x + __int_as_float(t);
}
// full sum within each 16-lane group (xor masks 1,2,7,15 span GF(2)^4)
__device__ __forceinline__ float red16(float x) {
  x = dpp_add<0xB1>(x);   // quad_perm xor1
  x = dpp_add<0x4E>(x);   // quad_perm xor2
  x = dpp_add<0x141>(x);  // row_half_mirror (xor7)
  x = dpp_add<0x140>(x);  // row_mirror (xor15)
  return x;
}

// ---------------------------------------------------------------------------
// FUSED kernel: per chunk block (b,c) = 32 rows:
//   phase A: emissions tile = hs[rows] @ W^T + b  -> LDS em_s + global em
//   phase B: numerator partial (wave 2) + log-semiring transfer matrix
//            (threads 0..80) on the in-LDS tile.
// Waves {0,1} cover rows 0..15 (k-halves 0/1), waves {2,3} rows 16..31.
// Each wave: 16 rows, 2 loads/row (1536 B), depth-2 in-place prefetch,
// 54 FMA + red16 per row, 4 masked LDS writes -> part[32][8][9].
__global__ __launch_bounds__(256, 4)
void emcrf(const float* __restrict__ hs, const float* __restrict__ W,
           const float* __restrict__ bias, const int* __restrict__ lab,
           const float* __restrict__ trans, const float* __restrict__ startT,
           float* __restrict__ em, float* __restrict__ Pout,
           float* __restrict__ numpart, int* __restrict__ cntpart,
           int* __restrict__ gcnt) {
  const int blk = blockIdx.x;
  const int b = blk >> 6, c = blk & 63;
  const int tid = threadIdx.x;
  const int lane = tid & 63;
  const int w = tid >> 6;
  const int half = w & 1;         // k-half
  const int rowg = (w >> 1) * 16; // row group base
  const int t0 = c * TCHUNK;
  if (blk == 0 && tid == 0) *gcnt = 0;  // re-arm fold finalize counter

  __shared__ float part[TCHUNK][8][9];  // 9.2 KB
  __shared__ float em_s[TCHUNK * LL];   // 1.15 KB
  __shared__ float Pbuf[2][81];
  __shared__ int lab_s[TCHUNK + 1];

  if (tid <= TCHUNK) {
    int g = t0 - 1 + tid;
    lab_s[tid] = (g >= 0) ? lab[b * SS + g] : 0;
  }

  // ---- phase A: GEMM ----
  const int kb = half * 384;
  float wr[LL][6];
#pragma unroll
  for (int l = 0; l < LL; ++l) {
    float4 t4 = *reinterpret_cast<const float4*>(W + l * HH + kb + lane * 4);
    float2 t2 = *reinterpret_cast<const float2*>(W + l * HH + kb + 256 + lane * 2);
    wr[l][0] = t4.x; wr[l][1] = t4.y; wr[l][2] = t4.z; wr[l][3] = t4.w;
    wr[l][4] = t2.x; wr[l][5] = t2.y;
  }

  const size_t rbase = (size_t)(b * SS + t0 + rowg) * HH + kb;
  const float* r0 = hs + rbase;
  float4 A4 = *reinterpret_cast<const float4*>(r0 + lane * 4);
  float2 A2 = *reinterpret_cast<const float2*>(r0 + 256 + lane * 2);
  const float* r1 = hs + rbase + HH;
  float4 B4 = *reinterpret_cast<const float4*>(r1 + lane * 4);
  float2 B2 = *reinterpret_cast<const float2*>(r1 + 256 + lane * 2);

  const int slot = half * 4 + (lane >> 4);
  const bool wlead = (lane & 15) == 0;

#pragma unroll
  for (int r = 0; r < 16; ++r) {
    float4 cur4 = (r & 1) ? B4 : A4;
    float2 cur2 = (r & 1) ? B2 : A2;
    if (r + 2 < 16) {  // refill consumed buffer for row r+2 (static)
      const float* rn = hs + rbase + (size_t)(r + 2) * HH;
      if (r & 1) {
        B4 = *reinterpret_cast<const float4*>(rn + lane * 4);
        B2 = *reinterpret_cast<const float2*>(rn + 256 + lane * 2);
      } else {
        A4 = *reinterpret_cast<const float4*>(rn + lane * 4);
        A2 = *reinterpret_cast<const float2*>(rn + 256 + lane * 2);
      }
    }
    const float h[6] = {cur4.x, cur4.y, cur4.z, cur4.w, cur2.x, cur2.y};
#pragma unroll
    for (int l = 0; l < LL; ++l) {
      float s = h[0] * wr[l][0];
#pragma unroll
      for (int q = 1; q < 6; ++q) s = fmaf(h[q], wr[l][q], s);
      s = red16(s);
      if (wlead) part[rowg + r][slot][l] = s;  // banks 9g mod 32: distinct
    }
  }
  __syncthreads();

  // combine 8 partials per (row,label) + bias -> LDS tile + global em
  float* emg = em + (size_t)(b * SS + t0) * LL;
  for (int j = tid; j < TCHUNK * LL; j += 256) {
    const int o = j / LL, l = j - o * LL;
    float s = bias[l];
#pragma unroll
    for (int q = 0; q < 8; ++q) s += part[o][q][l];
    em_s[j] = s;
    emg[j] = s;
  }
  __syncthreads();

  // ---- phase B ----
  // per-wave identical ballot of valid steps
  unsigned mask32 =
      (unsigned)__ballot((lane < 32) ? (lab_s[1 + lane] != -100) : false);

  // numerator partial: wave 2, lane = local step
  if (w == 2) {
    float sc = 0.f;
    if (lane < 32) {
      int lv = lab_s[1 + lane];
      int tg = (lv != -100) ? lv : 0;
      if (t0 + lane == 0) {
        sc = startT[tg] + em_s[tg];  // score0, unconditional
      } else if (lv != -100) {
        int pv = lab_s[lane];
        int tp = (pv != -100) ? pv : 0;
        sc = trans[tp * LL + tg] + em_s[lane * LL + tg];
      }
    }
#pragma unroll
    for (int off = 32; off; off >>= 1) sc += __shfl_xor(sc, off, 64);
    if (lane == 0) {
      numpart[blk] = sc;
      cntpart[blk] = __popc(mask32);
    }
  }

  // log-semiring recurrence, threads 0..80 (waves 0-1)
  const int i9 = tid / 9, j9 = tid % 9;
  float tc[9];
  if (tid < 81) {
#pragma unroll
    for (int k = 0; k < 9; ++k) tc[k] = trans[k * 9 + j9];
    Pbuf[0][tid] = (i9 == j9) ? 0.f : -1e30f;
  }
  __syncthreads();
  int cur = 0;
  const int ltstart = (c == 0) ? 1 : 0;  // t=0 is alpha0, not a matrix
  for (int lt = ltstart; lt < TCHUNK; ++lt) {
    if ((mask32 >> lt) & 1u) {
      if (tid < 81) {
        float v[9];
#pragma unroll
        for (int k = 0; k < 9; ++k) v[k] = Pbuf[cur][i9 * 9 + k] + tc[k];
        Pbuf[cur ^ 1][tid] = lse9(v) + em_s[lt * LL + j9];
      }
      __syncthreads();
      cur ^= 1;
    }
  }
  if (tid < 81) Pout[(size_t)blk * 81 + tid] = Pbuf[cur][tid];
}

// ---------------------------------------------------------------------------
// Kernel 2: per-batch tree fold (depth 6) + llh + fused finalize.
__global__ __launch_bounds__(128)
void crf_fold(const float* __restrict__ Pm, const float* __restrict__ em,
              const float* __restrict__ startT, const float* __restrict__ endT,
              const float* __restrict__ numpart, const int* __restrict__ cntpart,
              const int* __restrict__ lab, float* __restrict__ llh,
              int* __restrict__ gcnt, float* __restrict__ out) {
  const int b = blockIdx.x, tid = threadIdx.x;
  __shared__ __align__(16) float Abuf[64 * 81];
  __shared__ __align__(16) float Bbuf[32 * 81];

  const float* src = Pm + (size_t)b * NCHUNK * 81;
  for (int i = tid; i < 64 * 81 / 4; i += 128)
    reinterpret_cast<float4*>(Abuf)[i] = reinterpret_cast<const float4*>(src)[i];
  __syncthreads();

  float* pin = Abuf;
  float* pout = Bbuf;
  for (int n = 32;; n >>= 1) {
    for (int o = tid; o < n * 81; o += 128) {
      int m = o / 81, e = o % 81;
      int i = e / 9, j = e % 9;
      const float* M1 = pin + (2 * m) * 81;
      const float* M2 = pin + (2 * m + 1) * 81;
      float v[9];
#pragma unroll
      for (int k = 0; k < 9; ++k) v[k] = M1[i * 9 + k] + M2[k * 9 + j];
      pout[o] = lse9(v);
    }
    __syncthreads();
    if (n == 1) break;
    float* t = pin; pin = pout;
    pout = (pout == Bbuf) ? Abuf : t;
  }
  const float* fin = pout;

  float ns = 0.f;
  int cn = 0;
  if (tid < 64) {
    ns = numpart[b * 64 + tid];
    cn = cntpart[b * 64 + tid];
#pragma unroll
    for (int off = 32; off; off >>= 1) {
      ns += __shfl_xor(ns, off, 64);
      cn += __shfl_xor(cn, off, 64);
    }
  }
  if (tid == 0) {
    float a0[9], af[9], v[9];
#pragma unroll
    for (int j = 0; j < 9; ++j) a0[j] = startT[j] + em[(size_t)b * SS * LL + j];
#pragma unroll
    for (int j = 0; j < 9; ++j) {
#pragma unroll
      for (int k = 0; k < 9; ++k) v[k] = a0[k] + fin[k * 9 + j];
      af[j] = lse9(v);
    }
#pragma unroll
    for (int j = 0; j < 9; ++j) v[j] = af[j] + endT[j];
    float den = lse9(v);
    int se = cn - 1;
    int lt = lab[b * SS + se];
    if (lt == -100) lt = 0;
    llh[b] = (ns + endT[lt]) - den;

    __threadfence();
    int old = atomicAdd(gcnt, 1);
    if (old == BB - 1) {  // last block finalizes in fixed order
      __threadfence();
      float s = 0.f;
      for (int i = 0; i < BB; ++i)
        s += __hip_atomic_load(&llh[i], __ATOMIC_RELAXED,
                               __HIP_MEMORY_SCOPE_AGENT);
      out[0] = -s / (float)BB;
    }
  }
}

// ---------------------------------------------------------------------------
extern "C" void kernel_launch(void* const* d_in, const int* in_sizes, int n_in,
                              void* d_out, int out_size, void* d_ws, size_t ws_size,
                              hipStream_t stream) {
  const float* hs = (const float*)d_in[0];
  const float* W = (const float*)d_in[1];
  const float* bias = (const float*)d_in[2];
  const float* startT = (const float*)d_in[3];
  const float* endT = (const float*)d_in[4];
  const float* trans = (const float*)d_in[5];
  const int* labels = (const int*)d_in[6];

  float* out = (float*)d_out;  // out[0] = loss, out[1..] = emissions [B,S,L]
  float* em = out + 1;

  float* wsf = (float*)d_ws;
  float* llh = wsf;                        // [32]
  int* gcnt = (int*)(wsf + 32);            // [1]
  float* numpart = wsf + 64;               // [B*NCHUNK]
  int* cntpart = (int*)(wsf + 64 + 2048);  // [B*NCHUNK]
  float* Pm = wsf + 64 + 4096;             // [B*NCHUNK*81], 16B-aligned

  emcrf<<<BB * NCHUNK, 256, 0, stream>>>(hs, W, bias, labels, trans, startT,
                                         em, Pm, numpart, cntpart, gcnt);
  crf_fold<<<BB, 128, 0, stream>>>(Pm, em, startT, endT, numpart, cntpart,
                                   labels, llh, gcnt, out);
}